// Round 8
// baseline (243.176 us; speedup 1.0000x reference)
//
#include <hip/hip_runtime.h>

// ---------------- workspace layout (indices into uint32/float32 view) -------
// wsu[0] = min key, wsu[1] = max key (generic/atomic path only)
// wsu[2..257]   = hist[256]
// wsf[258..514] = edges[257]
// wsf[515] = vmin, wsf[516] = delta, wsf[517] = inv_delta, wsf[518] = thresh
// wsu[1024 .. 1024+2*npairs) = per-block (mn,mx) key pairs
// byte offset 32768: gray[npix]
static constexpr int HIST_OFF    = 2;
static constexpr int EDGES_OFF   = 258;
static constexpr int VMIN_OFF    = 515;
static constexpr int DELTA_OFF   = 516;
static constexpr int INVD_OFF    = 517;
static constexpr int THRESH_OFF  = 518;
static constexpr int SCRATCH_OFF = 1024;         // per-block minmax pairs
static constexpr size_t GRAY_BYTE_OFF = 32768;

typedef float nfloat4 __attribute__((ext_vector_type(4)));

__device__ __forceinline__ unsigned fkey(float x) {
    unsigned u = __float_as_uint(x);
    return (u & 0x80000000u) ? ~u : (u | 0x80000000u);
}
__device__ __forceinline__ float keyf(unsigned k) {
    return (k & 0x80000000u) ? __uint_as_float(k & 0x7FFFFFFFu)
                             : __uint_as_float(~k);
}
// gray = ((r*wr + g*wg) + b*wb), strict f32 rounding, NO fma contraction
__device__ __forceinline__ float gray1(float r, float g, float b) {
    float t0 = __fmul_rn(r, 0.2989f);
    float t1 = __fmul_rn(g, 0.5870f);
    float t2 = __fmul_rn(b, 0.1140f);
    return __fadd_rn(__fadd_rn(t0, t1), t2);
}

__device__ __forceinline__ void bin4(float x0, float x1, float x2, float x3,
                                     const float* eds, float vmin, float invd,
                                     unsigned* lh) {
    float xs[4] = {x0, x1, x2, x3};
#pragma unroll
    for (int j = 0; j < 4; ++j) {
        float x = xs[j];
        int b = (int)(__fmul_rn(__fsub_rn(x, vmin), invd));
        b = b < 0 ? 0 : (b > 255 ? 255 : b);
        while (b < 255 && x >= eds[b + 1]) ++b;   // exact searchsorted fixup
        while (b > 0 && x < eds[b]) --b;
        atomicAdd(&lh[b], 1u);
    }
}

// block-wide reduce of the per-block (mn,mx) scratch pairs (plain loads,
// L2-resident 8 KB). All threads get the final result.
__device__ __forceinline__ void reduce_pairs(const unsigned* __restrict__ wsu,
                                             int npairs, int t,
                                             unsigned& mn, unsigned& mx,
                                             unsigned* rmn, unsigned* rmx) {
    mn = 0xFFFFFFFFu; mx = 0u;
    for (int i = t; i < npairs; i += 256) {
        mn = min(mn, wsu[SCRATCH_OFF + 2 * i]);
        mx = max(mx, wsu[SCRATCH_OFF + 2 * i + 1]);
    }
    for (int off = 32; off > 0; off >>= 1) {
        mn = min(mn, (unsigned)__shfl_xor((int)mn, off, 64));
        mx = max(mx, (unsigned)__shfl_xor((int)mx, off, 64));
    }
    const int w = t >> 6;
    if ((t & 63) == 0) { rmn[w] = mn; rmx[w] = mx; }
    __syncthreads();
    mn = min(min(rmn[0], rmn[1]), min(rmn[2], rmn[3]));
    mx = max(max(rmx[0], rmx[1]), max(rmx[2], rmx[3]));
}

// =============== R13b: 3-kernel pipeline, atomic-thinned + plain stores =====
// R6 post-mortem: persistent fusion dead (coop 307us, spin-barrier 268us --
// barrier + agent-scope uncached polling). R5 structure (237.8) is kept.
// This round: (1) K2 grid 1024->256 blocks => global hist RMWs 262K->65K
// (R0-R3 showed same-address/line RMW serialization at the coherence point
// is worth tens of us); (2) K3 NT stores -> plain L2-writeback stores (the
// only 6.7 TB/s writer we measured -- the harness fill -- uses plain);
// (3) K2 exports edges/invd so K3 skips the redundant pair-reduce.
// (R7 was this same kernel with a const-write compile error; fixed.)

// ---------- K1: gray + per-block minmax (proven, ~42 us) --------------------
__global__ void __launch_bounds__(256)
gray_minmax_lds(const float* __restrict__ in, float* __restrict__ gray,
                unsigned* __restrict__ wsu, int npix4) {
    __shared__ float4 sb[4][2][192];
    __shared__ unsigned smn[4], smx[4];
    const float4* __restrict__ in4 = (const float4*)in;
    float4* __restrict__ gray4 = (float4*)gray;
    const int lane = threadIdx.x & 63;
    const int w = threadIdx.x >> 6;
    const int gw = blockIdx.x * 4 + w;
    const size_t base = (size_t)gw * 768;
    unsigned mn = 0xFFFFFFFFu, mx = 0u;

    // fold init: block 0 zeroes the global hist (visible to K2 via stream
    // ordering)
    if (blockIdx.x == 0) wsu[HIST_OFF + threadIdx.x] = 0u;

    float4 a0 = in4[base + lane];
    float4 a1 = in4[base + 64 + lane];
    float4 a2 = in4[base + 128 + lane];
    __builtin_amdgcn_sched_barrier(0);
    sb[w][0][lane]       = a0;
    sb[w][0][64 + lane]  = a1;
    sb[w][0][128 + lane] = a2;
    a0 = in4[base + 192 + lane];
    a1 = in4[base + 256 + lane];
    a2 = in4[base + 320 + lane];
    __builtin_amdgcn_sched_barrier(0);

#pragma unroll
    for (int t = 0; t < 4; ++t) {
        const int cb = t & 1;
        float4 c0 = sb[w][cb][3 * lane + 0];
        float4 c1 = sb[w][cb][3 * lane + 1];
        float4 c2 = sb[w][cb][3 * lane + 2];
        float g0 = gray1(c0.x, c0.y, c0.z);
        float g1 = gray1(c0.w, c1.x, c1.y);
        float g2 = gray1(c1.z, c1.w, c2.x);
        float g3 = gray1(c2.y, c2.z, c2.w);
        gray4[(size_t)gw * 256 + t * 64 + lane] = make_float4(g0, g1, g2, g3);
        unsigned k0 = fkey(g0), k1 = fkey(g1), k2 = fkey(g2), k3 = fkey(g3);
        mn = min(mn, min(min(k0, k1), min(k2, k3)));
        mx = max(mx, max(max(k0, k1), max(k2, k3)));
        if (t < 3) {
            sb[w][cb ^ 1][lane]       = a0;
            sb[w][cb ^ 1][64 + lane]  = a1;
            sb[w][cb ^ 1][128 + lane] = a2;
            if (t < 2) {
                a0 = in4[base + (size_t)(t + 2) * 192 + lane];
                a1 = in4[base + (size_t)(t + 2) * 192 + 64 + lane];
                a2 = in4[base + (size_t)(t + 2) * 192 + 128 + lane];
            }
            __builtin_amdgcn_sched_barrier(0);
        }
    }
    for (int off = 32; off > 0; off >>= 1) {
        mn = min(mn, (unsigned)__shfl_xor((int)mn, off, 64));
        mx = max(mx, (unsigned)__shfl_xor((int)mx, off, 64));
    }
    if (lane == 0) { smn[w] = mn; smx[w] = mx; }
    __syncthreads();
    if (threadIdx.x == 0) {
        mn = min(min(smn[0], smn[1]), min(smn[2], smn[3]));
        mx = max(max(smx[0], smx[1]), max(smx[2], smx[3]));
        wsu[SCRATCH_OFF + 2 * blockIdx.x]     = mn;
        wsu[SCRATCH_OFF + 2 * blockIdx.x + 1] = mx;
    }
}

// ---------- K2: edges + hist, 256 fat blocks (atomic-thinned) ---------------
// grid = EXACTLY 256 blocks x 256 threads; thread t of block b owns gray4
// indices {b*256 + t + k*65536 : k=0..nf4-1}; nf4 = npix4/65536 (mult of 8).
// Global hist flush: 256 blocks x 256 bins = 65K RMWs (was 262K).
__global__ void __launch_bounds__(256)
hist_fused2(const float* __restrict__ gray, unsigned* __restrict__ wsu,
            float* __restrict__ wsf, int npairs, int npix4) {
    __shared__ float eds[257];
    __shared__ unsigned lh[256];
    __shared__ unsigned rmn[4], rmx[4];
    const int t = threadIdx.x;
    unsigned mn, mx;
    reduce_pairs(wsu, npairs, t, mn, mx, rmn, rmx);
    const float vmin = keyf(mn);
    const float vmax = keyf(mx);
    const float delta = __fdiv_rn(__fsub_rn(vmax, vmin), 256.0f);
    const float invd = (delta > 0.0f) ? __fdiv_rn(1.0f, delta) : 0.0f;
    const float e = __fadd_rn(vmin, __fmul_rn((float)t, delta));
    eds[t] = e;
    if (t == 0) eds[256] = vmax;
    lh[t] = 0u;
    // export edges/params once for K3 (plain stores, stream-ordered)
    if (blockIdx.x == 0) {
        wsf[EDGES_OFF + t] = e;
        if (t == 0) {
            wsf[EDGES_OFF + 256] = vmax;
            wsf[VMIN_OFF]  = vmin;
            wsf[DELTA_OFF] = delta;
            wsf[INVD_OFF]  = invd;
        }
    }
    __syncthreads();

    const int nf4 = npix4 >> 16;                  // per-thread f4 count
    const int base = blockIdx.x * 256 + t;        // in [0, 65536)
    const float4* __restrict__ gray4 = (const float4*)gray;
    for (int it = 0; it < nf4; it += 8) {
        float4 g[8];
#pragma unroll
        for (int j = 0; j < 8; ++j)
            g[j] = gray4[(size_t)base + (size_t)(it + j) * 65536];
#pragma unroll
        for (int j = 0; j < 8; ++j)
            bin4(g[j].x, g[j].y, g[j].z, g[j].w, eds, vmin, invd, lh);
    }
    __syncthreads();
    if (lh[t] != 0u) atomicAdd(&wsu[HIST_OFF + t], lh[t]);
}

// ---------- K3: Otsu recompute + binarize (plain stores) --------------------
// grid = npix4/2048 blocks. Preamble loads edges from wsf (no pair-reduce),
// hist from wsu; serial cumsums on thread 0 (order-faithful), 255 parallel
// variance evals, first-max argmax. Binarize body: bpermute expand, PLAIN
// full-line stores (NT removed -- testing the NT-write-throttle theory).
__global__ void __launch_bounds__(256)
binarize_fused2(const float* __restrict__ gray,
                const unsigned* __restrict__ wsu,
                const float* __restrict__ wsf, float* __restrict__ out,
                int npix4) {
    __shared__ float eds[257];
    __shared__ float histf[256], centers[256];
    __shared__ float w1a[256], s1a[256], w2a[256], s2a[256];
    __shared__ float rbv[4];
    __shared__ int rbi[4];
    __shared__ float sthresh;
    const int t = threadIdx.x;
    const int lane = t & 63;
    const int w = t >> 6;

    eds[t] = wsf[EDGES_OFF + t];
    if (t == 0) eds[256] = wsf[EDGES_OFF + 256];
    histf[t] = (float)wsu[HIST_OFF + t];
    __syncthreads();
    centers[t] = __fmul_rn(__fadd_rn(eds[t], eds[t + 1]), 0.5f);
    __syncthreads();
    if (t == 0) {
        float ww = 0.0f, ss = 0.0f;
        for (int k = 255; k >= 0; --k) {           // backward cumsums (exact)
            ww = __fadd_rn(ww, histf[k]);
            ss = __fadd_rn(ss, __fmul_rn(histf[k], centers[k]));
            w2a[k] = ww;
            s2a[k] = ss;
        }
        ww = 0.0f; ss = 0.0f;
        for (int k = 0; k < 255; ++k) {            // forward cumsums (exact)
            ww = __fadd_rn(ww, histf[k]);
            ss = __fadd_rn(ss, __fmul_rn(histf[k], centers[k]));
            w1a[k] = ww;
            s1a[k] = ss;
        }
    }
    __syncthreads();
    float v = -1.0f;
    int ti = 256;
    if (t < 255) {                                 // parallel variance evals
        float m1 = __fdiv_rn(s1a[t], fmaxf(w1a[t], 1.0f));
        float m2 = __fdiv_rn(s2a[t + 1], fmaxf(w2a[t + 1], 1.0f));
        float d  = __fsub_rn(m1, m2);
        v  = __fmul_rn(__fmul_rn(w1a[t], w2a[t + 1]), __fmul_rn(d, d));
        ti = t;
    }
    for (int off = 32; off > 0; off >>= 1) {       // first-max argmax reduce
        float ov = __shfl_xor(v, off, 64);
        int oi = __shfl_xor(ti, off, 64);
        if (ov > v || (ov == v && oi < ti)) { v = ov; ti = oi; }
    }
    if (lane == 0) { rbv[w] = v; rbi[w] = ti; }
    __syncthreads();
    if (t == 0) {
        float bv = rbv[0]; int bi = rbi[0];
        for (int k = 1; k < 4; ++k)
            if (rbv[k] > bv || (rbv[k] == bv && rbi[k] < bi)) {
                bv = rbv[k]; bi = rbi[k];
            }
        sthresh = centers[bi];
    }
    __syncthreads();
    const float thr = sthresh;

    const nfloat4* gray4 = (const nfloat4*)gray;
    nfloat4* out4 = (nfloat4*)out;
    const int gw = blockIdx.x * 4 + w;
    const int ma = lane / 3,         qa = lane % 3;
    const int mb = (64 + lane) / 3,  qb = (64 + lane) % 3;
    const int mc = (128 + lane) / 3, qc = (128 + lane) % 3;
#pragma unroll
    for (int r = 0; r < 8; ++r) {
        const int gbase = gw * 512 + r * 64;
        nfloat4 gg = gray4[gbase + lane];
        unsigned u = (gg.x > thr ? 1u : 0u) |
                     (gg.y > thr ? 0x100u : 0u) |
                     (gg.z > thr ? 0x10000u : 0u) |
                     (gg.w > thr ? 0x1000000u : 0u);
        const size_t rb = 3 * (size_t)gbase;
#pragma unroll
        for (int k = 0; k < 3; ++k) {
            int m = (k == 0) ? ma : (k == 1) ? mb : mc;
            int q = (k == 0) ? qa : (k == 1) ? qb : qc;
            unsigned x = (unsigned)__builtin_amdgcn_ds_bpermute(4 * m, (int)u);
            float h0 = (x & 0xffu)       ? 1.0f : 0.0f;
            float h1 = (x & 0xff00u)     ? 1.0f : 0.0f;
            float h2 = (x & 0xff0000u)   ? 1.0f : 0.0f;
            float h3 = (x & 0xff000000u) ? 1.0f : 0.0f;
            nfloat4 o;
            o.x = (q == 0) ? h0 : (q == 1) ? h1 : h2;
            o.y = (q == 0) ? h0 : (q == 1) ? h1 : h3;
            o.z = (q == 0) ? h0 : (q == 1) ? h2 : h3;
            o.w = (q == 0) ? h1 : (q == 1) ? h2 : h3;
            out4[rb + 64 * k + lane] = o;          // plain store (NT removed)
        }
    }
}

// =============== generic multi-kernel fallback (any size, proven) ===========

__global__ void init_kernel(unsigned* __restrict__ wsu) {
    int i = threadIdx.x;
    if (i < 256) wsu[HIST_OFF + i] = 0u;
    if (i == 0) { wsu[0] = 0xFFFFFFFFu; wsu[1] = 0u; }
}

__global__ void __launch_bounds__(256)
gray_minmax_generic(const float* __restrict__ in, float* __restrict__ gray,
                    unsigned* __restrict__ wsu, int npix4) {
    __shared__ unsigned smn[4], smx[4];
    const float4* in4 = (const float4*)in;
    const int stride = gridDim.x * blockDim.x;
    unsigned mn = 0xFFFFFFFFu, mx = 0u;
    for (int t = blockIdx.x * blockDim.x + threadIdx.x; t < npix4; t += stride) {
        const float4* p = in4 + (size_t)t * 3;
        float4 c0 = p[0], c1 = p[1], c2 = p[2];
        float g0 = gray1(c0.x, c0.y, c0.z);
        float g1 = gray1(c0.w, c1.x, c1.y);
        float g2 = gray1(c1.z, c1.w, c2.x);
        float g3 = gray1(c2.y, c2.z, c2.w);
        if (gray) ((float4*)gray)[t] = make_float4(g0, g1, g2, g3);
        unsigned k0 = fkey(g0), k1 = fkey(g1), k2 = fkey(g2), k3 = fkey(g3);
        mn = min(mn, min(min(k0, k1), min(k2, k3)));
        mx = max(mx, max(max(k0, k1), max(k2, k3)));
    }
    for (int off = 32; off > 0; off >>= 1) {
        mn = min(mn, (unsigned)__shfl_xor((int)mn, off, 64));
        mx = max(mx, (unsigned)__shfl_xor((int)mx, off, 64));
    }
    int wave = threadIdx.x >> 6;
    if ((threadIdx.x & 63) == 0) { smn[wave] = mn; smx[wave] = mx; }
    __syncthreads();
    if (threadIdx.x == 0) {
        mn = min(min(smn[0], smn[1]), min(smn[2], smn[3]));
        mx = max(max(smx[0], smx[1]), max(smx[2], smx[3]));
        atomicMin(&wsu[0], mn);
        atomicMax(&wsu[1], mx);
    }
}

__global__ void edges_kernel(unsigned* __restrict__ wsu,
                             float* __restrict__ wsf) {
    const int i = threadIdx.x;
    unsigned mn = wsu[0], mx = wsu[1];
    const float vmin = keyf(mn);
    const float vmax = keyf(mx);
    const float delta = __fdiv_rn(__fsub_rn(vmax, vmin), 256.0f);
    wsf[EDGES_OFF + i] = __fadd_rn(vmin, __fmul_rn((float)i, delta));
    if (i == 0) {
        wsf[EDGES_OFF + 256] = vmax;
        wsf[VMIN_OFF]  = vmin;
        wsf[DELTA_OFF] = delta;
        wsf[INVD_OFF]  = (delta > 0.0f) ? __fdiv_rn(1.0f, delta) : 0.0f;
    }
}

__global__ void __launch_bounds__(256)
hist_kernel(const float* __restrict__ gray, const float* __restrict__ in,
            const float* __restrict__ wsf, unsigned* __restrict__ wsu,
            int npix4) {
    __shared__ float eds[257];
    __shared__ unsigned lh[256];
    for (int i = threadIdx.x; i < 257; i += blockDim.x)
        eds[i] = wsf[EDGES_OFF + i];
    if (threadIdx.x < 256) lh[threadIdx.x] = 0u;
    __syncthreads();
    const float vmin = eds[0];
    const float invd = wsf[INVD_OFF];
    const int stride = gridDim.x * blockDim.x;
    const int base = blockIdx.x * blockDim.x + threadIdx.x;
    for (int t = base; t < npix4; t += stride) {
        float4 g4;
        if (gray) g4 = ((const float4*)gray)[t];
        else {
            const float4* p = (const float4*)in + (size_t)t * 3;
            float4 c0 = p[0], c1 = p[1], c2 = p[2];
            g4 = make_float4(gray1(c0.x, c0.y, c0.z), gray1(c0.w, c1.x, c1.y),
                             gray1(c1.z, c1.w, c2.x), gray1(c2.y, c2.z, c2.w));
        }
        bin4(g4.x, g4.y, g4.z, g4.w, eds, vmin, invd, lh);
    }
    __syncthreads();
    if (threadIdx.x < 256 && lh[threadIdx.x] != 0u)
        atomicAdd(&wsu[HIST_OFF + threadIdx.x], lh[threadIdx.x]);
}

__global__ void otsu_kernel(const unsigned* __restrict__ wsu,
                            float* __restrict__ wsf) {
    __shared__ float histf[256];
    __shared__ float centers[256];
    __shared__ float w2a[256];
    __shared__ float s2a[256];
    int i = threadIdx.x;
    float e0 = wsf[EDGES_OFF + i];
    float e1 = wsf[EDGES_OFF + i + 1];
    centers[i] = __fmul_rn(__fadd_rn(e0, e1), 0.5f);
    histf[i] = (float)wsu[HIST_OFF + i];
    __syncthreads();
    if (i == 0) {
        float w = 0.0f, s = 0.0f;
        for (int t = 255; t >= 0; --t) {
            w = __fadd_rn(w, histf[t]);
            s = __fadd_rn(s, __fmul_rn(histf[t], centers[t]));
            w2a[t] = w;
            s2a[t] = s;
        }
        float w1 = 0.0f, s1 = 0.0f, best = -1.0f;
        int bidx = 0;
        for (int t = 0; t < 255; ++t) {
            w1 = __fadd_rn(w1, histf[t]);
            s1 = __fadd_rn(s1, __fmul_rn(histf[t], centers[t]));
            float m1 = __fdiv_rn(s1, fmaxf(w1, 1.0f));
            float m2 = __fdiv_rn(s2a[t + 1], fmaxf(w2a[t + 1], 1.0f));
            float d  = __fsub_rn(m1, m2);
            float v  = __fmul_rn(__fmul_rn(w1, w2a[t + 1]), __fmul_rn(d, d));
            if (v > best) { best = v; bidx = t; }
        }
        wsf[THRESH_OFF] = centers[bidx];
    }
}

__global__ void __launch_bounds__(256)
binarize_generic(const float* __restrict__ gray, const float* __restrict__ in,
                 const float* __restrict__ wsf, float* __restrict__ out,
                 int npix4) {
    const float thr = wsf[THRESH_OFF];
    const int stride = gridDim.x * blockDim.x;
    nfloat4* out4 = (nfloat4*)out;
    for (int t = blockIdx.x * blockDim.x + threadIdx.x; t < npix4; t += stride) {
        float4 g4;
        if (gray) g4 = ((const float4*)gray)[t];
        else {
            const float4* p = (const float4*)in + (size_t)t * 3;
            float4 c0 = p[0], c1 = p[1], c2 = p[2];
            g4 = make_float4(gray1(c0.x, c0.y, c0.z), gray1(c0.w, c1.x, c1.y),
                             gray1(c1.z, c1.w, c2.x), gray1(c2.y, c2.z, c2.w));
        }
        float b0 = (g4.x > thr) ? 1.0f : 0.0f;
        float b1 = (g4.y > thr) ? 1.0f : 0.0f;
        float b2 = (g4.z > thr) ? 1.0f : 0.0f;
        float b3 = (g4.w > thr) ? 1.0f : 0.0f;
        nfloat4* o = out4 + (size_t)t * 3;
        o[0] = (nfloat4){b0, b0, b0, b1};
        o[1] = (nfloat4){b1, b1, b2, b2};
        o[2] = (nfloat4){b2, b3, b3, b3};
    }
}

static void launch_generic(const float* in, float* out, unsigned* wsu,
                           float* wsf, float* gray, int npix4,
                           hipStream_t stream) {
    hipLaunchKernelGGL(init_kernel, dim3(1), dim3(256), 0, stream, wsu);
    hipLaunchKernelGGL(gray_minmax_generic, dim3(2048), dim3(256), 0,
                       stream, in, gray, wsu, npix4);
    hipLaunchKernelGGL(edges_kernel, dim3(1), dim3(256), 0, stream, wsu, wsf);
    hipLaunchKernelGGL(hist_kernel, dim3(1024), dim3(256), 0, stream,
                       gray, in, wsf, wsu, npix4);
    hipLaunchKernelGGL(otsu_kernel, dim3(1), dim3(256), 0, stream, wsu, wsf);
    hipLaunchKernelGGL(binarize_generic, dim3(2048), dim3(256), 0, stream,
                       gray, in, wsf, out, npix4);
}

extern "C" void kernel_launch(void* const* d_in, const int* in_sizes, int n_in,
                              void* d_out, int out_size, void* d_ws,
                              size_t ws_size, hipStream_t stream) {
    const float* in = (const float*)d_in[0];
    float* out = (float*)d_out;
    int npix  = out_size / 3;
    int npix4 = npix / 4;
    unsigned* wsu = (unsigned*)d_ws;
    float* wsf = (float*)d_ws;
    size_t need = GRAY_BYTE_OFF + (size_t)npix * sizeof(float);
    float* gray = (ws_size >= need)
                      ? (float*)((char*)d_ws + GRAY_BYTE_OFF)
                      : nullptr;

    // fast path: K2's exact tiling needs npix4 % (65536*8) == 0 (implies the
    // %1024 / %2048 requirements of K1/K3)
    const bool fast = gray && (npix4 % 524288 == 0);
    if (fast) {
        const int npairs = npix4 / 1024;          // K1 grid / scratch pairs
        const int nb3 = npix4 / 2048;             // K3 grid
        hipLaunchKernelGGL(gray_minmax_lds, dim3(npairs), dim3(256), 0,
                           stream, in, gray, wsu, npix4);
        hipLaunchKernelGGL(hist_fused2, dim3(256), dim3(256), 0, stream,
                           gray, wsu, wsf, npairs, npix4);
        hipLaunchKernelGGL(binarize_fused2, dim3(nb3), dim3(256), 0, stream,
                           gray, wsu, wsf, out, npix4);
    } else {
        launch_generic(in, out, wsu, wsf, gray, npix4, stream);
    }
}

// Round 9
// 239.101 us; speedup vs baseline: 1.0170x; 1.0170x over previous
//
#include <hip/hip_runtime.h>

// ---------------- workspace layout (indices into uint32/float32 view) -------
// wsu[0] = min key, wsu[1] = max key (generic/atomic path only)
// wsu[2..257]   = hist[256]
// wsf[258..514] = edges[257]      (generic path)
// wsf[515] = vmin, wsf[516] = delta, wsf[517] = inv_delta, wsf[518] = thresh
// wsu[1024 .. 1024+2*npairs) = per-block (mn,mx) key pairs
// byte offset 32768: gray[npix]
static constexpr int HIST_OFF    = 2;
static constexpr int EDGES_OFF   = 258;
static constexpr int VMIN_OFF    = 515;
static constexpr int DELTA_OFF   = 516;
static constexpr int INVD_OFF    = 517;
static constexpr int THRESH_OFF  = 518;
static constexpr int SCRATCH_OFF = 1024;         // per-block minmax pairs
static constexpr size_t GRAY_BYTE_OFF = 32768;

typedef float nfloat4 __attribute__((ext_vector_type(4)));

__device__ __forceinline__ unsigned fkey(float x) {
    unsigned u = __float_as_uint(x);
    return (u & 0x80000000u) ? ~u : (u | 0x80000000u);
}
__device__ __forceinline__ float keyf(unsigned k) {
    return (k & 0x80000000u) ? __uint_as_float(k & 0x7FFFFFFFu)
                             : __uint_as_float(~k);
}
// gray = ((r*wr + g*wg) + b*wb), strict f32 rounding, NO fma contraction
__device__ __forceinline__ float gray1(float r, float g, float b) {
    float t0 = __fmul_rn(r, 0.2989f);
    float t1 = __fmul_rn(g, 0.5870f);
    float t2 = __fmul_rn(b, 0.1140f);
    return __fadd_rn(__fadd_rn(t0, t1), t2);
}

__device__ __forceinline__ void bin4(float x0, float x1, float x2, float x3,
                                     const float* eds, float vmin, float invd,
                                     unsigned* lh) {
    float xs[4] = {x0, x1, x2, x3};
#pragma unroll
    for (int j = 0; j < 4; ++j) {
        float x = xs[j];
        int b = (int)(__fmul_rn(__fsub_rn(x, vmin), invd));
        b = b < 0 ? 0 : (b > 255 ? 255 : b);
        while (b < 255 && x >= eds[b + 1]) ++b;   // exact searchsorted fixup
        while (b > 0 && x < eds[b]) --b;
        atomicAdd(&lh[b], 1u);
    }
}

// block-wide reduce of the per-block (mn,mx) scratch pairs (plain loads,
// L2-resident). All threads get the final result.
__device__ __forceinline__ void reduce_pairs(const unsigned* __restrict__ wsu,
                                             int npairs, int t,
                                             unsigned& mn, unsigned& mx,
                                             unsigned* rmn, unsigned* rmx) {
    mn = 0xFFFFFFFFu; mx = 0u;
    for (int i = t; i < npairs; i += 256) {
        mn = min(mn, wsu[SCRATCH_OFF + 2 * i]);
        mx = max(mx, wsu[SCRATCH_OFF + 2 * i + 1]);
    }
    for (int off = 32; off > 0; off >>= 1) {
        mn = min(mn, (unsigned)__shfl_xor((int)mn, off, 64));
        mx = max(mx, (unsigned)__shfl_xor((int)mx, off, 64));
    }
    const int w = t >> 6;
    if ((t & 63) == 0) { rmn[w] = mn; rmx[w] = mx; }
    __syncthreads();
    mn = min(min(rmn[0], rmn[1]), min(rmn[2], rmn[3]));
    mx = max(max(rmx[0], rmx[1]), max(rmx[2], rmx[3]));
}

// =============== R14: R5 pipeline (proven 237.8) + 8-tile K1 ================
// R8 post-mortem: K2@256 blocks (occupancy loss on loads) and plain stores
// (write RFO amplification -- NT was originally a measured win) were a net
// -5.4us; both reverted to R5 form. Single change this round: K1 waves run
// 8 tiles instead of 4 (same LDS/occupancy; half the block prologue/epilogue
// and half the scratch pairs -> K2/K3 preamble halves). All grids = npix4/2048.

// ---------- K1: gray + per-block minmax, 8 tiles/wave -----------------------
__global__ void __launch_bounds__(256)
gray_minmax_lds(const float* __restrict__ in, float* __restrict__ gray,
                unsigned* __restrict__ wsu, int npix4) {
    __shared__ float4 sb[4][2][192];
    __shared__ unsigned smn[4], smx[4];
    const float4* __restrict__ in4 = (const float4*)in;
    float4* __restrict__ gray4 = (float4*)gray;
    const int lane = threadIdx.x & 63;
    const int w = threadIdx.x >> 6;
    const int gw = blockIdx.x * 4 + w;
    const size_t base = (size_t)gw * 1536;        // 8 tiles x 192 float4
    unsigned mn = 0xFFFFFFFFu, mx = 0u;

    // fold init: block 0 zeroes the global hist (visible to K2 via stream
    // ordering)
    if (blockIdx.x == 0) wsu[HIST_OFF + threadIdx.x] = 0u;

    float4 a0 = in4[base + lane];
    float4 a1 = in4[base + 64 + lane];
    float4 a2 = in4[base + 128 + lane];
    __builtin_amdgcn_sched_barrier(0);
    sb[w][0][lane]       = a0;
    sb[w][0][64 + lane]  = a1;
    sb[w][0][128 + lane] = a2;
    a0 = in4[base + 192 + lane];
    a1 = in4[base + 256 + lane];
    a2 = in4[base + 320 + lane];
    __builtin_amdgcn_sched_barrier(0);

#pragma unroll
    for (int t = 0; t < 8; ++t) {
        const int cb = t & 1;
        float4 c0 = sb[w][cb][3 * lane + 0];
        float4 c1 = sb[w][cb][3 * lane + 1];
        float4 c2 = sb[w][cb][3 * lane + 2];
        float g0 = gray1(c0.x, c0.y, c0.z);
        float g1 = gray1(c0.w, c1.x, c1.y);
        float g2 = gray1(c1.z, c1.w, c2.x);
        float g3 = gray1(c2.y, c2.z, c2.w);
        gray4[(size_t)gw * 512 + t * 64 + lane] = make_float4(g0, g1, g2, g3);
        unsigned k0 = fkey(g0), k1 = fkey(g1), k2 = fkey(g2), k3 = fkey(g3);
        mn = min(mn, min(min(k0, k1), min(k2, k3)));
        mx = max(mx, max(max(k0, k1), max(k2, k3)));
        if (t < 7) {
            sb[w][cb ^ 1][lane]       = a0;
            sb[w][cb ^ 1][64 + lane]  = a1;
            sb[w][cb ^ 1][128 + lane] = a2;
            if (t < 6) {
                a0 = in4[base + (size_t)(t + 2) * 192 + lane];
                a1 = in4[base + (size_t)(t + 2) * 192 + 64 + lane];
                a2 = in4[base + (size_t)(t + 2) * 192 + 128 + lane];
            }
            __builtin_amdgcn_sched_barrier(0);
        }
    }
    for (int off = 32; off > 0; off >>= 1) {
        mn = min(mn, (unsigned)__shfl_xor((int)mn, off, 64));
        mx = max(mx, (unsigned)__shfl_xor((int)mx, off, 64));
    }
    if (lane == 0) { smn[w] = mn; smx[w] = mx; }
    __syncthreads();
    if (threadIdx.x == 0) {
        mn = min(min(smn[0], smn[1]), min(smn[2], smn[3]));
        mx = max(max(smx[0], smx[1]), max(smx[2], smx[3]));
        wsu[SCRATCH_OFF + 2 * blockIdx.x]     = mn;
        wsu[SCRATCH_OFF + 2 * blockIdx.x + 1] = mx;
    }
}

// ---------- K2: per-block edges recompute + hist (R5 form) ------------------
// grid = npix4/2048 blocks; each thread: 8 coalesced gray-float4 loads.
__global__ void __launch_bounds__(256)
hist_fused(const float* __restrict__ gray, unsigned* __restrict__ wsu,
           int npairs, int npix4) {
    __shared__ float eds[257];
    __shared__ unsigned lh[256];
    __shared__ unsigned rmn[4], rmx[4];
    const int t = threadIdx.x;
    unsigned mn, mx;
    reduce_pairs(wsu, npairs, t, mn, mx, rmn, rmx);
    const float vmin = keyf(mn);
    const float vmax = keyf(mx);
    const float delta = __fdiv_rn(__fsub_rn(vmax, vmin), 256.0f);
    const float invd = (delta > 0.0f) ? __fdiv_rn(1.0f, delta) : 0.0f;
    eds[t] = __fadd_rn(vmin, __fmul_rn((float)t, delta));
    if (t == 0) eds[256] = vmax;
    lh[t] = 0u;
    __syncthreads();

    const int stride = gridDim.x * 256;
    const int base = blockIdx.x * 256 + t;
    float4 g[8];
#pragma unroll
    for (int j = 0; j < 8; ++j) g[j] = ((const float4*)gray)[base + j * stride];
#pragma unroll
    for (int j = 0; j < 8; ++j)
        bin4(g[j].x, g[j].y, g[j].z, g[j].w, eds, vmin, invd, lh);
    __syncthreads();
    if (lh[t] != 0u) atomicAdd(&wsu[HIST_OFF + t], lh[t]);
}

// ---------- K3: per-block Otsu recompute + binarize (R5 form, NT stores) ----
__global__ void __launch_bounds__(256)
binarize_fused(const float* __restrict__ gray, const unsigned* __restrict__ wsu,
               float* __restrict__ out, int npairs, int npix4) {
    __shared__ float eds[257];
    __shared__ float histf[256], centers[256];
    __shared__ float w1a[256], s1a[256], w2a[256], s2a[256];
    __shared__ unsigned rmn[4], rmx[4];
    __shared__ float rbv[4];
    __shared__ int rbi[4];
    __shared__ float sthresh;
    const int t = threadIdx.x;
    const int lane = t & 63;
    const int w = t >> 6;

    unsigned mn, mx;
    reduce_pairs(wsu, npairs, t, mn, mx, rmn, rmx);
    const float vmin = keyf(mn);
    const float vmax = keyf(mx);
    const float delta = __fdiv_rn(__fsub_rn(vmax, vmin), 256.0f);
    eds[t] = __fadd_rn(vmin, __fmul_rn((float)t, delta));
    if (t == 0) eds[256] = vmax;
    histf[t] = (float)wsu[HIST_OFF + t];
    __syncthreads();
    centers[t] = __fmul_rn(__fadd_rn(eds[t], eds[t + 1]), 0.5f);
    __syncthreads();
    if (t == 0) {
        float ww = 0.0f, ss = 0.0f;
        for (int k = 255; k >= 0; --k) {           // backward cumsums (exact)
            ww = __fadd_rn(ww, histf[k]);
            ss = __fadd_rn(ss, __fmul_rn(histf[k], centers[k]));
            w2a[k] = ww;
            s2a[k] = ss;
        }
        ww = 0.0f; ss = 0.0f;
        for (int k = 0; k < 255; ++k) {            // forward cumsums (exact)
            ww = __fadd_rn(ww, histf[k]);
            ss = __fadd_rn(ss, __fmul_rn(histf[k], centers[k]));
            w1a[k] = ww;
            s1a[k] = ss;
        }
    }
    __syncthreads();
    float v = -1.0f;
    int ti = 256;
    if (t < 255) {                                 // parallel variance evals
        float m1 = __fdiv_rn(s1a[t], fmaxf(w1a[t], 1.0f));
        float m2 = __fdiv_rn(s2a[t + 1], fmaxf(w2a[t + 1], 1.0f));
        float d  = __fsub_rn(m1, m2);
        v  = __fmul_rn(__fmul_rn(w1a[t], w2a[t + 1]), __fmul_rn(d, d));
        ti = t;
    }
    for (int off = 32; off > 0; off >>= 1) {       // first-max argmax reduce
        float ov = __shfl_xor(v, off, 64);
        int oi = __shfl_xor(ti, off, 64);
        if (ov > v || (ov == v && oi < ti)) { v = ov; ti = oi; }
    }
    if (lane == 0) { rbv[w] = v; rbi[w] = ti; }
    __syncthreads();
    if (t == 0) {
        float bv = rbv[0]; int bi = rbi[0];
        for (int k = 1; k < 4; ++k)
            if (rbv[k] > bv || (rbv[k] == bv && rbi[k] < bi)) {
                bv = rbv[k]; bi = rbi[k];
            }
        sthresh = centers[bi];
    }
    __syncthreads();
    const float thr = sthresh;

    // binarize body (proven bpermute expand + NT full-line stores)
    const nfloat4* gray4 = (const nfloat4*)gray;
    nfloat4* out4 = (nfloat4*)out;
    const int gw = blockIdx.x * 4 + w;
    const int ma = lane / 3,         qa = lane % 3;
    const int mb = (64 + lane) / 3,  qb = (64 + lane) % 3;
    const int mc = (128 + lane) / 3, qc = (128 + lane) % 3;
#pragma unroll
    for (int r = 0; r < 8; ++r) {
        const int gbase = gw * 512 + r * 64;
        nfloat4 gg = gray4[gbase + lane];
        unsigned u = (gg.x > thr ? 1u : 0u) |
                     (gg.y > thr ? 0x100u : 0u) |
                     (gg.z > thr ? 0x10000u : 0u) |
                     (gg.w > thr ? 0x1000000u : 0u);
        const size_t rb = 3 * (size_t)gbase;
#pragma unroll
        for (int k = 0; k < 3; ++k) {
            int m = (k == 0) ? ma : (k == 1) ? mb : mc;
            int q = (k == 0) ? qa : (k == 1) ? qb : qc;
            unsigned x = (unsigned)__builtin_amdgcn_ds_bpermute(4 * m, (int)u);
            float h0 = (x & 0xffu)       ? 1.0f : 0.0f;
            float h1 = (x & 0xff00u)     ? 1.0f : 0.0f;
            float h2 = (x & 0xff0000u)   ? 1.0f : 0.0f;
            float h3 = (x & 0xff000000u) ? 1.0f : 0.0f;
            nfloat4 o;
            o.x = (q == 0) ? h0 : (q == 1) ? h1 : h2;
            o.y = (q == 0) ? h0 : (q == 1) ? h1 : h3;
            o.z = (q == 0) ? h0 : (q == 1) ? h2 : h3;
            o.w = (q == 0) ? h1 : (q == 1) ? h2 : h3;
            __builtin_nontemporal_store(o, &out4[rb + 64 * k + lane]);
        }
    }
}

// =============== generic multi-kernel fallback (any size, proven) ===========

__global__ void init_kernel(unsigned* __restrict__ wsu) {
    int i = threadIdx.x;
    if (i < 256) wsu[HIST_OFF + i] = 0u;
    if (i == 0) { wsu[0] = 0xFFFFFFFFu; wsu[1] = 0u; }
}

__global__ void __launch_bounds__(256)
gray_minmax_generic(const float* __restrict__ in, float* __restrict__ gray,
                    unsigned* __restrict__ wsu, int npix4) {
    __shared__ unsigned smn[4], smx[4];
    const float4* in4 = (const float4*)in;
    const int stride = gridDim.x * blockDim.x;
    unsigned mn = 0xFFFFFFFFu, mx = 0u;
    for (int t = blockIdx.x * blockDim.x + threadIdx.x; t < npix4; t += stride) {
        const float4* p = in4 + (size_t)t * 3;
        float4 c0 = p[0], c1 = p[1], c2 = p[2];
        float g0 = gray1(c0.x, c0.y, c0.z);
        float g1 = gray1(c0.w, c1.x, c1.y);
        float g2 = gray1(c1.z, c1.w, c2.x);
        float g3 = gray1(c2.y, c2.z, c2.w);
        if (gray) ((float4*)gray)[t] = make_float4(g0, g1, g2, g3);
        unsigned k0 = fkey(g0), k1 = fkey(g1), k2 = fkey(g2), k3 = fkey(g3);
        mn = min(mn, min(min(k0, k1), min(k2, k3)));
        mx = max(mx, max(max(k0, k1), max(k2, k3)));
    }
    for (int off = 32; off > 0; off >>= 1) {
        mn = min(mn, (unsigned)__shfl_xor((int)mn, off, 64));
        mx = max(mx, (unsigned)__shfl_xor((int)mx, off, 64));
    }
    int wave = threadIdx.x >> 6;
    if ((threadIdx.x & 63) == 0) { smn[wave] = mn; smx[wave] = mx; }
    __syncthreads();
    if (threadIdx.x == 0) {
        mn = min(min(smn[0], smn[1]), min(smn[2], smn[3]));
        mx = max(max(smx[0], smx[1]), max(smx[2], smx[3]));
        atomicMin(&wsu[0], mn);
        atomicMax(&wsu[1], mx);
    }
}

__global__ void edges_kernel(unsigned* __restrict__ wsu,
                             float* __restrict__ wsf) {
    const int i = threadIdx.x;
    unsigned mn = wsu[0], mx = wsu[1];
    const float vmin = keyf(mn);
    const float vmax = keyf(mx);
    const float delta = __fdiv_rn(__fsub_rn(vmax, vmin), 256.0f);
    wsf[EDGES_OFF + i] = __fadd_rn(vmin, __fmul_rn((float)i, delta));
    if (i == 0) {
        wsf[EDGES_OFF + 256] = vmax;
        wsf[VMIN_OFF]  = vmin;
        wsf[DELTA_OFF] = delta;
        wsf[INVD_OFF]  = (delta > 0.0f) ? __fdiv_rn(1.0f, delta) : 0.0f;
    }
}

__global__ void __launch_bounds__(256)
hist_kernel(const float* __restrict__ gray, const float* __restrict__ in,
            const float* __restrict__ wsf, unsigned* __restrict__ wsu,
            int npix4) {
    __shared__ float eds[257];
    __shared__ unsigned lh[256];
    for (int i = threadIdx.x; i < 257; i += blockDim.x)
        eds[i] = wsf[EDGES_OFF + i];
    if (threadIdx.x < 256) lh[threadIdx.x] = 0u;
    __syncthreads();
    const float vmin = eds[0];
    const float invd = wsf[INVD_OFF];
    const int stride = gridDim.x * blockDim.x;
    const int base = blockIdx.x * blockDim.x + threadIdx.x;
    for (int t = base; t < npix4; t += stride) {
        float4 g4;
        if (gray) g4 = ((const float4*)gray)[t];
        else {
            const float4* p = (const float4*)in + (size_t)t * 3;
            float4 c0 = p[0], c1 = p[1], c2 = p[2];
            g4 = make_float4(gray1(c0.x, c0.y, c0.z), gray1(c0.w, c1.x, c1.y),
                             gray1(c1.z, c1.w, c2.x), gray1(c2.y, c2.z, c2.w));
        }
        bin4(g4.x, g4.y, g4.z, g4.w, eds, vmin, invd, lh);
    }
    __syncthreads();
    if (threadIdx.x < 256 && lh[threadIdx.x] != 0u)
        atomicAdd(&wsu[HIST_OFF + threadIdx.x], lh[threadIdx.x]);
}

__global__ void otsu_kernel(const unsigned* __restrict__ wsu,
                            float* __restrict__ wsf) {
    __shared__ float histf[256];
    __shared__ float centers[256];
    __shared__ float w2a[256];
    __shared__ float s2a[256];
    int i = threadIdx.x;
    float e0 = wsf[EDGES_OFF + i];
    float e1 = wsf[EDGES_OFF + i + 1];
    centers[i] = __fmul_rn(__fadd_rn(e0, e1), 0.5f);
    histf[i] = (float)wsu[HIST_OFF + i];
    __syncthreads();
    if (i == 0) {
        float w = 0.0f, s = 0.0f;
        for (int t = 255; t >= 0; --t) {
            w = __fadd_rn(w, histf[t]);
            s = __fadd_rn(s, __fmul_rn(histf[t], centers[t]));
            w2a[t] = w;
            s2a[t] = s;
        }
        float w1 = 0.0f, s1 = 0.0f, best = -1.0f;
        int bidx = 0;
        for (int t = 0; t < 255; ++t) {
            w1 = __fadd_rn(w1, histf[t]);
            s1 = __fadd_rn(s1, __fmul_rn(histf[t], centers[t]));
            float m1 = __fdiv_rn(s1, fmaxf(w1, 1.0f));
            float m2 = __fdiv_rn(s2a[t + 1], fmaxf(w2a[t + 1], 1.0f));
            float d  = __fsub_rn(m1, m2);
            float v  = __fmul_rn(__fmul_rn(w1, w2a[t + 1]), __fmul_rn(d, d));
            if (v > best) { best = v; bidx = t; }
        }
        wsf[THRESH_OFF] = centers[bidx];
    }
}

__global__ void __launch_bounds__(256)
binarize_generic(const float* __restrict__ gray, const float* __restrict__ in,
                 const float* __restrict__ wsf, float* __restrict__ out,
                 int npix4) {
    const float thr = wsf[THRESH_OFF];
    const int stride = gridDim.x * blockDim.x;
    nfloat4* out4 = (nfloat4*)out;
    for (int t = blockIdx.x * blockDim.x + threadIdx.x; t < npix4; t += stride) {
        float4 g4;
        if (gray) g4 = ((const float4*)gray)[t];
        else {
            const float4* p = (const float4*)in + (size_t)t * 3;
            float4 c0 = p[0], c1 = p[1], c2 = p[2];
            g4 = make_float4(gray1(c0.x, c0.y, c0.z), gray1(c0.w, c1.x, c1.y),
                             gray1(c1.z, c1.w, c2.x), gray1(c2.y, c2.z, c2.w));
        }
        float b0 = (g4.x > thr) ? 1.0f : 0.0f;
        float b1 = (g4.y > thr) ? 1.0f : 0.0f;
        float b2 = (g4.z > thr) ? 1.0f : 0.0f;
        float b3 = (g4.w > thr) ? 1.0f : 0.0f;
        nfloat4* o = out4 + (size_t)t * 3;
        o[0] = (nfloat4){b0, b0, b0, b1};
        o[1] = (nfloat4){b1, b1, b2, b2};
        o[2] = (nfloat4){b2, b3, b3, b3};
    }
}

static void launch_generic(const float* in, float* out, unsigned* wsu,
                           float* wsf, float* gray, int npix4,
                           hipStream_t stream) {
    hipLaunchKernelGGL(init_kernel, dim3(1), dim3(256), 0, stream, wsu);
    hipLaunchKernelGGL(gray_minmax_generic, dim3(2048), dim3(256), 0,
                       stream, in, gray, wsu, npix4);
    hipLaunchKernelGGL(edges_kernel, dim3(1), dim3(256), 0, stream, wsu, wsf);
    hipLaunchKernelGGL(hist_kernel, dim3(1024), dim3(256), 0, stream,
                       gray, in, wsf, wsu, npix4);
    hipLaunchKernelGGL(otsu_kernel, dim3(1), dim3(256), 0, stream, wsu, wsf);
    hipLaunchKernelGGL(binarize_generic, dim3(2048), dim3(256), 0, stream,
                       gray, in, wsf, out, npix4);
}

extern "C" void kernel_launch(void* const* d_in, const int* in_sizes, int n_in,
                              void* d_out, int out_size, void* d_ws,
                              size_t ws_size, hipStream_t stream) {
    const float* in = (const float*)d_in[0];
    float* out = (float*)d_out;
    int npix  = out_size / 3;
    int npix4 = npix / 4;
    unsigned* wsu = (unsigned*)d_ws;
    float* wsf = (float*)d_ws;
    size_t need = GRAY_BYTE_OFF + (size_t)npix * sizeof(float);
    float* gray = (ws_size >= need)
                      ? (float*)((char*)d_ws + GRAY_BYTE_OFF)
                      : nullptr;

    const bool fast = gray && (npix4 % 2048 == 0);
    if (fast) {
        const int nb = npix4 / 2048;              // grid for all 3 kernels
        hipLaunchKernelGGL(gray_minmax_lds, dim3(nb), dim3(256), 0,
                           stream, in, gray, wsu, npix4);
        hipLaunchKernelGGL(hist_fused, dim3(nb), dim3(256), 0, stream,
                           gray, wsu, nb, npix4);
        hipLaunchKernelGGL(binarize_fused, dim3(nb), dim3(256), 0, stream,
                           gray, wsu, out, nb, npix4);
    } else {
        launch_generic(in, out, wsu, wsf, gray, npix4, stream);
    }
}